// Round 7
// baseline (2171.550 us; speedup 1.0000x reference)
//
#include <hip/hip_runtime.h>
#include <math.h>

#define EPSV 1e-5f

typedef unsigned short u16t;
typedef unsigned int u32t;
typedef __attribute__((ext_vector_type(8))) short bf16x8;
typedef __attribute__((ext_vector_type(8))) unsigned short u16x8;
typedef __attribute__((ext_vector_type(4))) unsigned short u16x4;
typedef __attribute__((ext_vector_type(4))) float f32x4;

#define N_P  31719424   // 64*44*44*256 elements (xt / p layout)
#define N_CW 589824     // conv weights
#define N_QW 131072     // qkv weights per axial

// fragment-ordered split-bf16 weights / bf16 rel tables (rewritten every launch)
__device__ __align__(16) u16t g_cwhi[N_CW], g_cwlo[N_CW];
__device__ __align__(16) u16t g_qwhi[2][N_QW], g_qwlo[2][N_QW];
__device__ __align__(16) u16t g_relq[2][3072];   // [d=96][c=32] bf16 of rel[c][d], rows 0..31
__device__ __align__(16) u16t g_relk[2][3072];   // [d=96][c=32] of rel[32+c][d]
__device__ __align__(16) u16t g_relv[2][6144];   // [c=64][d=96] of 0.1*rel[64+c][d]
// BN constant tables
__device__ __align__(16) float g_bnq_s[2][512], g_bnq_h[2][512];
__device__ __align__(16) float g_out_s0[2][256], g_out_s1[2][256], g_out_h[2][256];
__device__ float g_bnsf[2][12];   // [g]=sqk, [4+g]=0.1*sqr, [8+g]=0.1*skr

__device__ __forceinline__ u16t f2bf_rn(float f) {
    u32t u = __float_as_uint(f);
    u32t r = u + 0x7FFFu + ((u >> 16) & 1u);
    return (u16t)(r >> 16);
}
__device__ __forceinline__ float bf2f(u16t h) {
    return __uint_as_float(((u32t)h) << 16);
}

// ---------------------------------------------------------------------------
// Patchify + transpose x -> channels-last split-bf16 xt[n][y][x][c].
// ---------------------------------------------------------------------------
__global__ __launch_bounds__(256)
void transpose_x(const float* __restrict__ x,
                 u16t* __restrict__ xth, u16t* __restrict__ xtl)
{
    __shared__ u16t th[64][90];
    __shared__ u16t tl[64][90];
    const int cg = blockIdx.x, yy = blockIdx.y, b = blockIdx.z;
    const int t = threadIdx.x;
    const float* src = x + ((size_t)(b * 256 + cg * 64) * 88 + yy) * 88;
    for (int e = t; e < 5632; e += 256) {
        int c = e / 88, xx = e - c * 88;
        float v = src[(size_t)c * 7744 + xx];
        u16t hi = f2bf_rn(v);
        u16t lo = f2bf_rn(v - bf2f(hi));
        th[c][xx] = hi;
        tl[c][xx] = lo;
    }
    __syncthreads();
    const int i2 = (yy >= 44);
    const int yl = yy - 44 * i2;
    for (int u = t; u < 5632; u += 256) {
        int xx = u >> 6, c = u & 63;
        int i4 = (xx >= 44);
        int xl = xx - 44 * i4;
        int n = b * 4 + i2 * 2 + i4;
        size_t idx = ((size_t)(n * 44 + yl) * 44 + xl) * 256 + cg * 64 + c;
        xth[idx] = th[c][xx];
        xtl[idx] = tl[c][xx];
    }
}

// ---------------------------------------------------------------------------
__global__ __launch_bounds__(256)
void wsplit_conv(const float* __restrict__ cw)
{
    int idx = blockIdx.x * 256 + threadIdx.x;
    if (idx >= N_CW) return;
    int tap = idx % 9;
    int rem = idx / 9;
    int ci = rem & 255, co = rem >> 8;
    float w = cw[idx];
    u16t hi = f2bf_rn(w);
    u16t lo = f2bf_rn(w - bf2f(hi));
    int cit = ci >> 5, ci5 = ci & 31, ci8 = ci5 >> 3, e = ci5 & 7;
    int didx = (((cit * 9 + tap) * 4 + ci8) * 256 + co) * 8 + e;
    g_cwhi[didx] = hi;
    g_cwlo[didx] = lo;
}

__global__ __launch_bounds__(256)
void wsplit_qkv(const float* __restrict__ wh_, const float* __restrict__ ww_)
{
    int idx = blockIdx.x * 256 + threadIdx.x;
    if (idx >= 2 * N_QW) return;
    int sel = idx >> 17;
    int id  = idx & (N_QW - 1);
    float w = (sel ? ww_ : wh_)[id];
    u16t hi = f2bf_rn(w);
    u16t lo = f2bf_rn(w - bf2f(hi));
    int o = id >> 8, c = id & 255;
    int kt = c >> 5, ci8 = (c >> 3) & 3, e = c & 7;
    int didx = ((kt * 4 + ci8) * 512 + o) * 8 + e;
    g_qwhi[sel][didx] = hi;
    g_qwlo[sel][didx] = lo;
}

__global__ __launch_bounds__(256)
void wsplit_rel(const float* __restrict__ rh, const float* __restrict__ rw)
{
    int idx = blockIdx.x * 256 + threadIdx.x;
    if (idx >= 24576) return;
    int sel = idx >= 12288;
    int id  = idx - sel * 12288;
    const float* rel = sel ? rw : rh;
    if (id < 3072) {
        int d = id >> 5, c = id & 31;
        g_relq[sel][id] = (d < 87) ? f2bf_rn(rel[c * 87 + d]) : (u16t)0;
    } else if (id < 6144) {
        int j = id - 3072;
        int d = j >> 5, c = j & 31;
        g_relk[sel][j] = (d < 87) ? f2bf_rn(rel[(32 + c) * 87 + d]) : (u16t)0;
    } else {
        int j = id - 6144;
        int c = j / 96, d = j - c * 96;
        g_relv[sel][j] = (d < 87) ? f2bf_rn(0.1f * rel[(64 + c) * 87 + d]) : (u16t)0;
    }
}

// BN constant tables: bn_qkv s/h per channel; bn_out fused pair; bn_sim scales.
__global__ __launch_bounds__(256)
void wsplit_bn(const float* __restrict__ hq, const float* __restrict__ hs, const float* __restrict__ ho,
               const float* __restrict__ wq, const float* __restrict__ ws, const float* __restrict__ wo)
{
    int idx = blockIdx.x * 256 + threadIdx.x;
    if (idx >= 1560) return;
    int sel = idx >= 780;
    int id  = idx - sel * 780;
    const float* bq = sel ? wq : hq;
    const float* bs = sel ? ws : hs;
    const float* bo = sel ? wo : ho;
    if (id < 512) {
        float s = bq[id] * rsqrtf(bq[1536 + id] + EPSV);
        g_bnq_s[sel][id] = s;
        g_bnq_h[sel][id] = bq[512 + id] - bq[1024 + id] * s;
    } else if (id < 768) {
        int cf = id - 512;
        int o0 = 2 * cf, o1 = o0 + 1;
        float s0 = bo[o0] * rsqrtf(bo[1536 + o0] + EPSV);
        float s1 = bo[o1] * rsqrtf(bo[1536 + o1] + EPSV);
        g_out_s0[sel][cf] = s0;
        g_out_s1[sel][cf] = s1;
        g_out_h[sel][cf] = (bo[512 + o0] - bo[1024 + o0] * s0)
                         + (bo[512 + o1] - bo[1024 + o1] * s1);
    } else {
        int k = id - 768;            // 0..11: which*4+g
        int gg = k & 3, which = k >> 2;
        float s = bs[which * 4 + gg] * rsqrtf(bs[36 + which * 4 + gg] + EPSV);
        if (which) s *= 0.1f;        // qr/kr terms carry the 0.1
        g_bnsf[sel][which * 4 + gg] = s;
    }
}

// ---------------------------------------------------------------------------
// Axial attention, full-MFMA, one block per column, 4 groups in-loop.
// LDS 50384 B -> 3 blocks/CU. Regions (time-shared):
//   X stage (P0/P1): Xh @0 (24576) + Xl @24576 (24576)
//   attention:  Qh@0 Ql@3072 Kh@6144 Kl@9216 | Vh@12288 Vl@20480
//               Ph@28672 Pl@34816 | SC f32 [48][49] @40960 (9424)
//               S2 bf16 [48][96] overlays Q/K @0 (9216, Q/K dead by then)
// Barriers/group: dump | P3a MFMA | scatter | softmax | SV+store  (5)
// ---------------------------------------------------------------------------
#define OFF_XL 24576
#define OFF_QH 0
#define OFF_QL 3072
#define OFF_KH 6144
#define OFF_KL 9216
#define OFF_VH 12288
#define OFF_VL 20480
#define OFF_PH 28672
#define OFF_PL 34816
#define OFF_SC 40960
#define OFF_S2 0

template<int WIDTH>
__global__ __launch_bounds__(256, 3)
void axial_kernel(const u16t* __restrict__ sh, const u16t* __restrict__ sl,
                  const u16t* __restrict__ resh, const u16t* __restrict__ resl,
                  u16t* __restrict__ outh, u16t* __restrict__ outl,
                  int sel)
{
    __shared__ __align__(128) char smem[50384];

    const int blk = blockIdx.x;
    const int n   = blk / 44;
    const int col = blk - n * 44;
    const int t = threadIdx.x;
    const int wv = t >> 6, lane = t & 63;
    const int l15 = lane & 15, l16 = lane >> 4;
    float* SCf = (float*)(smem + OFF_SC);

    // ---- P0: stage X split-bf16 [i=48][c=256] swizzled (rows 44..47 zero) ----
    if (!WIDTH) {
        for (int e = t; e < 6144; e += 256) {
            int i = e >> 7, cp = e & 127;
            u32t vH = 0, vL = 0;
            if (i < 44) {
                size_t s0 = ((size_t)(n * 44 + i) * 44 + col) * 256 + cp * 2;
                vH = *(const u32t*)(sh + s0);
                vL = *(const u32t*)(sl + s0);
            }
            u32t a = ((u32t)(i * 512 + cp * 4)) ^ (((u32t)(i & 7)) << 4);
            *(u32t*)(smem + a) = vH;
            *(u32t*)(smem + OFF_XL + a) = vL;
        }
    } else {
        const u16t* ph = sh + (size_t)(n * 44 + col) * 44 * 256;
        const u16t* pl = sl + (size_t)(n * 44 + col) * 44 * 256;
        for (int e = t; e < 6144; e += 256) {
            int i = e >> 7, cp = e & 127;
            u32t vH = 0, vL = 0;
            if (i < 44) {
                vH = *(const u32t*)(ph + i * 256 + cp * 2);
                vL = *(const u32t*)(pl + i * 256 + cp * 2);
            }
            u32t a = ((u32t)(i * 512 + cp * 4)) ^ (((u32t)(i & 7)) << 4);
            *(u32t*)(smem + a) = vH;
            *(u32t*)(smem + OFF_XL + a) = vL;
        }
    }
    __syncthreads();

    // ---- P1: qkv GEMM, all 512 rows; acc[8][3], o = (mf*4+wv)*16 + l15 ----
    f32x4 acc[8][3];
    #pragma unroll
    for (int mf = 0; mf < 8; ++mf)
        #pragma unroll
        for (int nf = 0; nf < 3; ++nf) acc[mf][nf] = (f32x4)0.f;
    {
        const u16t* WH = g_qwhi[sel];
        const u16t* WL = g_qwlo[sel];
        for (int kt = 0; kt < 8; ++kt) {
            bf16x8 bh[3], bl[3];
            #pragma unroll
            for (int nf = 0; nf < 3; ++nf) {
                int i = nf * 16 + l15;
                u32t a = ((u32t)(i * 512 + kt * 64 + l16 * 16)) ^ (((u32t)(i & 7)) << 4);
                bh[nf] = *(const bf16x8*)(smem + a);
                bl[nf] = *(const bf16x8*)(smem + OFF_XL + a);
            }
            #pragma unroll
            for (int mf = 0; mf < 8; ++mf) {
                int o = (mf * 4 + wv) * 16 + l15;
                size_t wb = ((size_t)(kt * 4 + l16) * 512 + o) * 8;
                bf16x8 ah = *(const bf16x8*)(WH + wb);
                bf16x8 al = *(const bf16x8*)(WL + wb);
                #pragma unroll
                for (int nf = 0; nf < 3; ++nf) {
                    acc[mf][nf] = __builtin_amdgcn_mfma_f32_16x16x32_bf16(ah, bh[nf], acc[mf][nf], 0, 0, 0);
                    acc[mf][nf] = __builtin_amdgcn_mfma_f32_16x16x32_bf16(al, bh[nf], acc[mf][nf], 0, 0, 0);
                    acc[mf][nf] = __builtin_amdgcn_mfma_f32_16x16x32_bf16(ah, bl[nf], acc[mf][nf], 0, 0, 0);
                }
            }
        }
    }
    __syncthreads();   // X dead; LDS becomes group buffers

    // ---- zero V pad cols (j=44..63) once; dumps never touch them ----
    for (int e = t; e < 1280; e += 256) {
        int arr = e & 1, q = e >> 1;
        int c = q / 10, k = q - c * 10;
        u32t ad = ((u32t)(c * 128 + 88 + k * 4)) ^ (((u32t)(c & 7)) << 4);
        *(u32t*)(smem + (arr ? OFF_VL : OFF_VH) + ad) = 0;
    }

    for (int g = 0; g < 4; ++g) {
        // ---- select this group's fragments (static indices) ----
        f32x4 fq[3], fv[3];
        #pragma unroll
        for (int nf = 0; nf < 3; ++nf) { fq[nf] = acc[0][nf]; fv[nf] = acc[1][nf]; }
        #pragma unroll
        for (int m = 1; m < 4; ++m) {
            if (g == m) {
                #pragma unroll
                for (int nf = 0; nf < 3; ++nf) { fq[nf] = acc[2 * m][nf]; fv[nf] = acc[2 * m + 1][nf]; }
            }
        }

        // ---- P2: dump q/k/v with table-BN ----
        #pragma unroll
        for (int r = 0; r < 4; ++r) {
            int ol = wv * 16 + l16 * 4 + r;       // 0..63
            {   // q (ol<32) / k (ol>=32)
                int o = g * 128 + ol;
                float s = g_bnq_s[sel][o], h = g_bnq_h[sel][o];
                #pragma unroll
                for (int nf = 0; nf < 3; ++nf) {
                    int i = nf * 16 + l15;
                    float val = fq[nf][r] * s + h;
                    u16t hi = f2bf_rn(val);
                    u16t lo = f2bf_rn(val - bf2f(hi));
                    if (ol < 32) {
                        u32t a = ((u32t)(i * 64 + ol * 2)) ^ (((u32t)(i & 7)) << 4);
                        *(u16t*)(smem + OFF_QH + a) = hi;
                        *(u16t*)(smem + OFF_QL + a) = lo;
                    } else {
                        int c = ol - 32;
                        u32t a = ((u32t)(i * 64 + c * 2)) ^ (((u32t)(i & 7)) << 4);
                        *(u16t*)(smem + OFF_KH + a) = hi;
                        *(u16t*)(smem + OFF_KL + a) = lo;
                    }
                }
            }
            {   // v channel c = ol
                int c = ol;
                int o = g * 128 + 64 + c;
                float s = g_bnq_s[sel][o], h = g_bnq_h[sel][o];
                #pragma unroll
                for (int nf = 0; nf < 3; ++nf) {
                    int i = nf * 16 + l15;
                    if (i < 44) {
                        float val = fv[nf][r] * s + h;
                        u16t hi = f2bf_rn(val);
                        u16t lo = f2bf_rn(val - bf2f(hi));
                        u32t a = ((u32t)(c * 128 + i * 2)) ^ (((u32t)(c & 7)) << 4);
                        *(u16t*)(smem + OFF_VH + a) = hi;
                        *(u16t*)(smem + OFF_VL + a) = lo;
                    }
                }
            }
        }
        __syncthreads();

        const float sqk  = g_bnsf[sel][g];
        const float sqr1 = g_bnsf[sel][4 + g];
        const float skr1 = g_bnsf[sel][8 + g];

        // ---- P3a: qk (x sqk) -> SC ; R = Q.rel_q, KR = K.rel_k -> regs ----
        #pragma unroll
        for (int fi = 0; fi < 3; ++fi) {
            int f = fi * 4 + wv;
            if (f < 9) {
                int mf = f / 3, nf = f % 3;
                int ia = mf * 16 + l15;
                u32t aq = ((u32t)(ia * 64 + l16 * 16)) ^ (((u32t)(ia & 7)) << 4);
                bf16x8 qh = *(const bf16x8*)(smem + OFF_QH + aq);
                bf16x8 ql = *(const bf16x8*)(smem + OFF_QL + aq);
                int jb = nf * 16 + l15;
                u32t ak = ((u32t)(jb * 64 + l16 * 16)) ^ (((u32t)(jb & 7)) << 4);
                bf16x8 kh = *(const bf16x8*)(smem + OFF_KH + ak);
                bf16x8 kl = *(const bf16x8*)(smem + OFF_KL + ak);
                f32x4 d = (f32x4)0.f;
                d = __builtin_amdgcn_mfma_f32_16x16x32_bf16(qh, kh, d, 0, 0, 0);
                d = __builtin_amdgcn_mfma_f32_16x16x32_bf16(ql, kh, d, 0, 0, 0);
                d = __builtin_amdgcn_mfma_f32_16x16x32_bf16(qh, kl, d, 0, 0, 0);
                #pragma unroll
                for (int r = 0; r < 4; ++r) {
                    int i = mf * 16 + l16 * 4 + r;
                    SCf[i * 49 + nf * 16 + l15] = d[r] * sqk;
                }
            }
        }
        f32x4 rfr[5], kfr[5];
        #pragma unroll
        for (int fi = 0; fi < 5; ++fi) {
            int f = fi * 4 + wv;
            if (f < 18) {
                int mf = f / 6, nf = f % 6;
                int ia = mf * 16 + l15;
                u32t aq = ((u32t)(ia * 64 + l16 * 16)) ^ (((u32t)(ia & 7)) << 4);
                bf16x8 qh = *(const bf16x8*)(smem + OFF_QH + aq);
                bf16x8 rb = *(const bf16x8*)(&g_relq[sel][(nf * 16 + l15) * 32 + l16 * 8]);
                f32x4 d = (f32x4)0.f;
                rfr[fi] = __builtin_amdgcn_mfma_f32_16x16x32_bf16(qh, rb, d, 0, 0, 0);
                u32t ak = ((u32t)(ia * 64 + l16 * 16)) ^ (((u32t)(ia & 7)) << 4);
                bf16x8 kh = *(const bf16x8*)(smem + OFF_KH + ak);
                bf16x8 rk = *(const bf16x8*)(&g_relk[sel][(nf * 16 + l15) * 32 + l16 * 8]);
                f32x4 d2 = (f32x4)0.f;
                kfr[fi] = __builtin_amdgcn_mfma_f32_16x16x32_bf16(kh, rk, d2, 0, 0, 0);
            }
        }
        __syncthreads();

        // ---- P3b: scatter-add rq/kr into SC (atomic: R vs KR may collide) ----
        #pragma unroll
        for (int fi = 0; fi < 5; ++fi) {
            int f = fi * 4 + wv;
            if (f < 18) {
                int mf = f / 6, nf = f % 6;
                int dd = nf * 16 + l15;
                #pragma unroll
                for (int r = 0; r < 4; ++r) {
                    int i = mf * 16 + l16 * 4 + r;     // R row (q-row) / KR row (k-col)
                    int j = i - dd + 43;                // R: (i, j); KR: (j', i) with same formula
                    if (i < 44 && j >= 0 && j < 44) {
                        atomicAdd(&SCf[i * 49 + j], rfr[fi][r] * sqr1);
                        atomicAdd(&SCf[j * 49 + i], kfr[fi][r] * skr1);
                    }
                }
            }
        }
        __syncthreads();

        // ---- P3c: fused softmax -> P (hi/lo) + S2 (bf16 via shuffles) ----
        for (int i = wv; i < 44; i += 4) {
            float v = (lane < 44) ? SCf[i * 49 + lane] : -INFINITY;
            float m = v;
            #pragma unroll
            for (int off = 32; off; off >>= 1) m = fmaxf(m, __shfl_xor(m, off));
            float ex = (lane < 44) ? __expf(v - m) : 0.f;
            float ssum = ex;
            #pragma unroll
            for (int off = 32; off; off >>= 1) ssum += __shfl_xor(ssum, off);
            float p = ex / ssum;                         // lanes >=44 -> 0
            u16t hi = f2bf_rn(p);
            u16t lo = f2bf_rn(p - bf2f(hi));
            u32t ap = ((u32t)(i * 128 + lane * 2)) ^ (((u32t)(i & 7)) << 4);
            *(u16t*)(smem + OFF_PH + ap) = hi;
            *(u16t*)(smem + OFF_PL + ap) = lo;
            // S2[i][d] = P[i][i-d+43]; band d in [i, i+43]
            int j1 = i + 43 - lane;                      // d = lane
            float s1v = __shfl(p, j1 & 63);
            s1v = (j1 >= 0 && j1 < 44) ? s1v : 0.f;
            u32t a1 = ((u32t)(i * 192 + lane * 2)) ^ (((u32t)(i & 7)) << 4);
            *(u16t*)(smem + OFF_S2 + a1) = f2bf_rn(s1v);
            if (lane < 32) {                             // d = lane+64 (64..95)
                int j2 = i - 21 - lane;
                float s2v = __shfl(p, j2 & 63);
                s2v = (j2 >= 0) ? s2v : 0.f;
                u32t a2 = ((u32t)(i * 192 + (lane + 64) * 2)) ^ (((u32t)(i & 7)) << 4);
                *(u16t*)(smem + OFF_S2 + a2) = f2bf_rn(s2v);
            }
        }
        __syncthreads();

        // ---- P3d: SV + SVE MFMA, table bn_out, direct packed store ----
        #pragma unroll
        for (int fi = 0; fi < 3; ++fi) {
            int f = fi * 4 + wv;                         // < 12 always
            int mf = f / 3, nf = f % 3;
            f32x4 dsv = (f32x4)0.f, dsve = (f32x4)0.f;
            #pragma unroll
            for (int kt = 0; kt < 2; ++kt) {
                int ca = mf * 16 + l15;
                u32t av = ((u32t)(ca * 128 + kt * 64 + l16 * 16)) ^ (((u32t)(ca & 7)) << 4);
                bf16x8 vh = *(const bf16x8*)(smem + OFF_VH + av);
                bf16x8 vl = *(const bf16x8*)(smem + OFF_VL + av);
                int ib = nf * 16 + l15;
                u32t ap = ((u32t)(ib * 128 + kt * 64 + l16 * 16)) ^ (((u32t)(ib & 7)) << 4);
                bf16x8 ph = *(const bf16x8*)(smem + OFF_PH + ap);
                bf16x8 pl = *(const bf16x8*)(smem + OFF_PL + ap);
                dsv = __builtin_amdgcn_mfma_f32_16x16x32_bf16(vh, ph, dsv, 0, 0, 0);
                dsv = __builtin_amdgcn_mfma_f32_16x16x32_bf16(vl, ph, dsv, 0, 0, 0);
                dsv = __builtin_amdgcn_mfma_f32_16x16x32_bf16(vh, pl, dsv, 0, 0, 0);
            }
            #pragma unroll
            for (int kt = 0; kt < 3; ++kt) {
                int ca = mf * 16 + l15;
                bf16x8 ar = *(const bf16x8*)(&g_relv[sel][ca * 96 + kt * 32 + l16 * 8]);
                int ib = nf * 16 + l15;
                u32t as = ((u32t)(ib * 192 + kt * 64 + l16 * 16)) ^ (((u32t)(ib & 7)) << 4);
                bf16x8 s2 = *(const bf16x8*)(smem + OFF_S2 + as);
                dsve = __builtin_amdgcn_mfma_f32_16x16x32_bf16(ar, s2, dsve, 0, 0, 0);
            }
            // store: 4 consecutive channels cf0..cf0+3 at row i
            int i = nf * 16 + l15;
            if (i < 44) {
                int cf0 = g * 64 + mf * 16 + l16 * 4;
                f32x4 s0 = *(const f32x4*)&g_out_s0[sel][cf0];
                f32x4 s1 = *(const f32x4*)&g_out_s1[sel][cf0];
                f32x4 hh = *(const f32x4*)&g_out_h[sel][cf0];
                size_t idx;
                if (!WIDTH) idx = ((size_t)(n * 44 + i) * 44 + col) * 256 + cf0;
                else        idx = ((size_t)(n * 44 + col) * 44 + i) * 256 + cf0;
                f32x4 val;
                #pragma unroll
                for (int r = 0; r < 4; ++r)
                    val[r] = s0[r] * dsv[r] + s1[r] * dsve[r] + hh[r];
                if (WIDTH) {
                    u16x4 rh = *(const u16x4*)(resh + idx);
                    u16x4 rl = *(const u16x4*)(resl + idx);
                    #pragma unroll
                    for (int r = 0; r < 4; ++r) val[r] += bf2f(rh[r]) + bf2f(rl[r]);
                }
                u16x4 oh, ol;
                #pragma unroll
                for (int r = 0; r < 4; ++r) {
                    u16t hi = f2bf_rn(val[r]);
                    oh[r] = hi;
                    ol[r] = f2bf_rn(val[r] - bf2f(hi));
                }
                *(u16x4*)(outh + idx) = oh;
                *(u16x4*)(outl + idx) = ol;
            }
        }
        __syncthreads();   // S2/Q/K/V/P/SC reused next group
    }
}

// ---------------------------------------------------------------------------
// 3x3 SAME conv, split-bf16 MFMA implicit GEMM (validated round 2, unchanged)
// ---------------------------------------------------------------------------
__global__ __launch_bounds__(256)
void conv_kernel(const u16t* __restrict__ phi,
                 const u16t* __restrict__ plo,
                 const float* __restrict__ cb,
                 float* __restrict__ out)
{
    __shared__ __align__(16) u16t Xs2[2][4 * 50 * 32];

    const int yb = blockIdx.x, n = blockIdx.y;
    const int y0 = yb * 2;
    const int b = n >> 2, i2 = (n >> 1) & 1, i4 = n & 1;
    const int t = threadIdx.x;
    const int wv = t >> 6, lane = t & 63;
    const int l15 = lane & 15, l16 = lane >> 4;

    f32x4 acc[4][6];
    #pragma unroll
    for (int mf = 0; mf < 4; ++mf)
        #pragma unroll
        for (int nf = 0; nf < 6; ++nf) acc[mf][nf] = (f32x4)0.f;

    char* lds = (char*)&Xs2[0][0];

    for (int cit = 0; cit < 8; ++cit) {
        const int ci0 = cit * 32;
        __syncthreads();
        for (int m = t; m < 1600; m += 256) {
            int ci8 = m & 3;
            int rem = m >> 2;
            int colm = rem % 50;
            int rr  = rem / 50;
            int arr = rr >> 2, rowidx = rr & 3;
            int gy = y0 - 1 + rowidx, gx = colm - 1;
            u16x8 v = (u16x8)0;
            if (gy >= 0 && gy < 44 && gx >= 0 && gx < 44) {
                const u16t* src = (arr ? plo : phi)
                    + (size_t)((n * 44 + gy) * 44 + gx) * 256 + ci0 + ci8 * 8;
                v = *(const u16x8*)src;
            }
            u32t addr = (u32t)((rowidx * 50 + colm) * 64 + ci8 * 16);
            addr ^= ((colm & 7) << 4);
            *(u16x8*)(lds + arr * 12800 + addr) = v;
        }
        __syncthreads();

        for (int tap = 0; tap < 9; ++tap) {
            const int dy = tap / 3, dx = tap % 3;
            const size_t wb = ((size_t)((cit * 9 + tap) * 4 + l16) * 256 + wv * 64 + l15) * 8;
            const u16x8* wh = (const u16x8*)(g_cwhi + wb);
            const u16x8* wl = (const u16x8*)(g_cwlo + wb);
            bf16x8 ah[4], al[4];
            #pragma unroll
            for (int mf = 0; mf < 4; ++mf) {
                ah[mf] = (bf16x8)wh[mf * 16];
                al[mf] = (bf16x8)wl[mf * 16];
            }
            int colr = l15 + dx;
            u32t rbase = (u32t)((dy * 50 + colr) * 64 + l16 * 16);
            rbase ^= ((colr & 7) << 4);
            const char* hb = lds + rbase;

            #pragma unroll
            for (int nf = 0; nf < 6; ++nf) {
                const int ry = nf / 3, cbk = nf % 3;
                const int off = ry * 3200 + cbk * 1024;
                bf16x8 bh = *(const bf16x8*)(hb + off);
                bf16x8 bl = *(const bf16x8*)(hb + 12800 + off);
                #pragma unroll
                for (int mf = 0; mf < 4; ++mf) {
                    acc[mf][nf] = __builtin_amdgcn_mfma_f32_16x16x32_bf16(ah[mf], bh, acc[mf][nf], 0, 0, 0);
                    acc[mf][nf] = __builtin_amdgcn_mfma_f32_16x16x32_bf16(al[mf], bh, acc[mf][nf], 0, 0, 0);
                    acc[mf][nf] = __builtin_amdgcn_mfma_f32_16x16x32_bf16(ah[mf], bl, acc[mf][nf], 0, 0, 0);
                }
            }
        }
    }

    #pragma unroll
    for (int mf = 0; mf < 4; ++mf) {
        const int cobase = wv * 64 + mf * 16 + l16 * 4;
        float bias[4];
        #pragma unroll
        for (int r = 0; r < 4; ++r) bias[r] = cb[cobase + r];
        #pragma unroll
        for (int nf = 0; nf < 6; ++nf) {
            const int ry = nf / 3, cbk = nf % 3;
            const int x = cbk * 16 + l15;
            if (x < 44) {
                const int y = y0 + ry;
                #pragma unroll
                for (int r = 0; r < 4; ++r) {
                    const int co = cobase + r;
                    out[((size_t)(b * 256 + co) * 88 + i2 * 44 + y) * 88 + i4 * 44 + x]
                        = acc[mf][nf][r] + bias[r];
                }
            }
        }
    }
}

extern "C" void kernel_launch(void* const* d_in, const int* in_sizes, int n_in,
                              void* d_out, int out_size, void* d_ws, size_t ws_size,
                              hipStream_t stream)
{
    (void)in_sizes; (void)n_in; (void)out_size; (void)ws_size;

    const float* x        = (const float*)d_in[0];
    const float* h_qkv_w  = (const float*)d_in[1];
    const float* h_bn_qkv = (const float*)d_in[2];
    const float* h_bn_sim = (const float*)d_in[3];
    const float* h_bn_out = (const float*)d_in[4];
    const float* h_rel    = (const float*)d_in[5];
    const float* w_qkv_w  = (const float*)d_in[6];
    const float* w_bn_qkv = (const float*)d_in[7];
    const float* w_bn_sim = (const float*)d_in[8];
    const float* w_bn_out = (const float*)d_in[9];
    const float* w_rel    = (const float*)d_in[10];
    const float* conv_w   = (const float*)d_in[11];
    const float* conv_b   = (const float*)d_in[12];

    u16t* xth = (u16t*)d_ws;
    u16t* xtl = xth + N_P;
    u16t* p1h = xtl + N_P;
    u16t* p1l = p1h + N_P;
    float* o  = (float*)d_out;

    transpose_x<<<dim3(4, 88, 16), 256, 0, stream>>>(x, xth, xtl);
    wsplit_conv<<<(N_CW + 255) / 256, 256, 0, stream>>>(conv_w);
    wsplit_qkv<<<(2 * N_QW + 255) / 256, 256, 0, stream>>>(h_qkv_w, w_qkv_w);
    wsplit_rel<<<96, 256, 0, stream>>>(h_rel, w_rel);
    wsplit_bn<<<7, 256, 0, stream>>>(h_bn_qkv, h_bn_sim, h_bn_out,
                                     w_bn_qkv, w_bn_sim, w_bn_out);

    // height-axis: xt -> p1
    axial_kernel<0><<<2816, 256, 0, stream>>>(xth, xtl, nullptr, nullptr, p1h, p1l, 0);
    // width-axis: p1 -> p1 (in place, block-owns-slice), residual from xt
    axial_kernel<1><<<2816, 256, 0, stream>>>(p1h, p1l, xth, xtl, p1h, p1l, 1);
    conv_kernel<<<dim3(22, 64), 256, 0, stream>>>(p1h, p1l, conv_b, o);
}